// Round 1
// baseline (4243.161 us; speedup 1.0000x reference)
//
#include <hip/hip_runtime.h>
#include <math.h>

#define ALPHA 0.5f
#define BETA  2.0e-4f   // 0.02 * 0.1 * 0.1
#define DELTA 0.1f
#define N_ITER 10

// err[s,y,x] = sum_{a,b,c} x[z+a-2, y+b-2, x+c-2] * psf[a,b,c]  -  slices[s,y,x]
// (lax.conv_general_dilated = cross-correlation, zero 'SAME' padding), z = s*stride
__global__ void srr_err_kernel(const float* __restrict__ x,
                               const float* __restrict__ slices,
                               const float* __restrict__ psf,
                               const int* __restrict__ stride_p,
                               float* __restrict__ err,
                               int D, int H, int W, int n_slices) {
    __shared__ float sp[125];
    const int t = threadIdx.x;
    if (t < 125) sp[t] = psf[t];
    __syncthreads();

    const int xi = t;           // blockDim.x == W
    const int y  = blockIdx.y;
    const int s  = blockIdx.z;
    const int stride = *stride_p;
    const int z = s * stride;
    const int HW = H * W;

    float acc = 0.0f;
    #pragma unroll
    for (int a = 0; a < 5; ++a) {
        const int zz = z + a - 2;
        if (zz < 0 || zz >= D) continue;
        #pragma unroll
        for (int b = 0; b < 5; ++b) {
            const int yy = y + b - 2;
            if (yy < 0 || yy >= H) continue;
            const float* row = x + zz * HW + yy * W;
            const float* pr  = sp + a * 25 + b * 5;
            #pragma unroll
            for (int c = 0; c < 5; ++c) {
                const int xc = xi + c - 2;
                if (xc < 0 || xc >= W) continue;
                acc += row[xc] * pr[c];
            }
        }
    }
    const int o = s * HW + y * W + xi;
    err[o] = acc - slices[o];
}

// x_out = x - ALPHA * ( At(err) + BETA * dR(x) ), optional final relu.
// At: correlation of zero-stuffed err volume with flipped psf (pre-flipped in LDS).
__global__ void srr_update_kernel(const float* __restrict__ x,
                                  const float* __restrict__ err,
                                  const float* __restrict__ psf,
                                  const int* __restrict__ stride_p,
                                  float* __restrict__ xout,
                                  int D, int H, int W, int n_slices,
                                  int apply_relu) {
    __shared__ float sp[125];
    const int t = threadIdx.x;
    if (t < 125) sp[t] = psf[124 - t];   // flipped psf: sp[a][b][c] = psf[4-a][4-b][4-c]
    __syncthreads();

    const int xi = t;           // blockDim.x == W
    const int y  = blockIdx.y;
    const int z  = blockIdx.z;
    const int stride = *stride_p;
    const int HW = H * W;

    // data-term gradient: At(err)[z,y,x]
    float g = 0.0f;
    #pragma unroll
    for (int a = 0; a < 5; ++a) {
        const int zz = z + a - 2;
        if (zz < 0 || zz >= D) continue;
        const int s = zz / stride;
        if (s * stride != zz || s >= n_slices) continue;
        #pragma unroll
        for (int b = 0; b < 5; ++b) {
            const int yy = y + b - 2;
            if (yy < 0 || yy >= H) continue;
            const float* row = err + s * HW + yy * W;
            const float* pr  = sp + a * 25 + b * 5;
            #pragma unroll
            for (int c = 0; c < 5; ++c) {
                const int xc = xi + c - 2;
                if (xc < 0 || xc >= W) continue;
                g += row[xc] * pr[c];
            }
        }
    }

    // regularizer gradient (zero on the 1-voxel border)
    float reg = 0.0f;
    const int idx = z * HW + y * W + xi;
    const float v0 = x[idx];
    if (z >= 1 && z < D - 1 && y >= 1 && y < H - 1 && xi >= 1 && xi < W - 1) {
        #pragma unroll
        for (int dz = -1; dz <= 1; ++dz) {
            #pragma unroll
            for (int dy = -1; dy <= 1; ++dy) {
                #pragma unroll
                for (int dx = -1; dx <= 1; ++dx) {
                    if (dx == 0 && dy == 0 && dz == 0) continue;
                    const float v1 = x[(z + dz) * HW + (y + dy) * W + (xi + dx)];
                    const float dv = v0 - v1;
                    const float wgt = 1.0f / ((float)(dx*dx + dy*dy + dz*dz) * (DELTA * DELTA));
                    const float dvw = dv * wgt;
                    reg += dvw * rsqrtf(1.0f + dv * dvw);
                }
            }
        }
    }

    float xn = v0 - ALPHA * (g + BETA * reg);
    if (apply_relu) xn = fmaxf(xn, 0.0f);
    xout[idx] = xn;
}

extern "C" void kernel_launch(void* const* d_in, const int* in_sizes, int n_in,
                              void* d_out, int out_size, void* d_ws, size_t ws_size,
                              hipStream_t stream) {
    // inputs: 0=theta (unused), 1=slices, 2=volume, 3=psf, 4=stride
    const float* slices = (const float*)d_in[1];
    const float* volume = (const float*)d_in[2];
    const float* psf    = (const float*)d_in[3];
    const int*   strd   = (const int*)d_in[4];

    const int D = 192, H = 192, W = 192;
    const int n_slices = in_sizes[1] / (H * W);   // 96

    float* x_ws  = (float*)d_ws;                           // 192^3 floats
    float* err   = x_ws + (size_t)D * H * W;               // n_slices*H*W floats
    float* x_out = (float*)d_out;                          // pong buffer / final output

    dim3 blk(W, 1, 1);
    dim3 grdA(1, H, n_slices);
    dim3 grdB(1, H, D);

    const float* src = volume;
    for (int it = 0; it < N_ITER; ++it) {
        float* dst = (it & 1) ? x_out : x_ws;
        srr_err_kernel<<<grdA, blk, 0, stream>>>(src, slices, psf, strd, err,
                                                 D, H, W, n_slices);
        srr_update_kernel<<<grdB, blk, 0, stream>>>(src, err, psf, strd, dst,
                                                    D, H, W, n_slices,
                                                    (it == N_ITER - 1) ? 1 : 0);
        src = dst;
    }
}

// Round 2
// 1734.142 us; speedup vs baseline: 2.4468x; 2.4468x over previous
//
#include <hip/hip_runtime.h>
#include <math.h>

#define ALPHA 0.5f
#define BETA  2.0e-4f   // 0.02 * 0.1 * 0.1
#define DELTA 0.1f
#define N_ITER 10

#define DD 192
#define HH 192
#define WW 192
#define HWW (192*192)
#define CH 24          // y-rows marched per block
#define NSMAX 3        // max err slices overlapping a z-window (stride>=2)

// ---------------------------------------------------------------------------
// K1: err[s,y,x] = conv3(x, psf)[s*stride, y, x] - slices[s,y,x]
// Separable: psf[a][b][c] ~= wz[a]*wy[b]*wx[c] (exact: input psf is an outer
// product of a 1-D Gaussian; factors extracted on-device from marginals).
// Block: (slice s, y-chunk). 192 threads = one x-row. LDS ring of x-convolved
// rows (5 z-planes x 5 y-ring), zero-padded halos => no per-tap bounds checks.
// ---------------------------------------------------------------------------
__global__ __launch_bounds__(192) void srr_err_k(
    const float* __restrict__ x, const float* __restrict__ slices,
    const float* __restrict__ psf, const int* __restrict__ stride_p,
    float* __restrict__ err, int n_slices)
{
    __shared__ float spsf[128];
    __shared__ float wz[5], wy[5], wx[5], wsum[16];
    __shared__ float raw[5][200];      // raw x rows, halo 2 each side (pads stay 0)
    __shared__ float cx[5][5][192];    // x-convolved rows, [z-plane][y-ring][x]

    const int t = threadIdx.x;
    if (t < 125) spsf[t] = psf[t];
    if (t >= 128 && t < 148) {         // zero raw halos once
        int q = t - 128, r = q >> 2, p = q & 3;
        raw[r][(p < 2) ? p : (192 + p)] = 0.f;
    }
    __syncthreads();
    // marginals (parallel partial sums)
    if (t < 5)               { float s=0; for (int k=0;k<25;++k) s+=spsf[t*25+k]; wsum[t]=s; }
    else if (t>=8 && t<13)   { int b=t-8;  float s=0; for(int a=0;a<5;++a) for(int c=0;c<5;++c) s+=spsf[a*25+b*5+c]; wsum[t-3]=s; }
    else if (t>=16 && t<21)  { int c=t-16; float s=0; for(int a=0;a<5;++a) for(int b=0;b<5;++b) s+=spsf[a*25+b*5+c]; wsum[t-6]=s; }
    __syncthreads();
    if (t == 0) {
        float T = wsum[0]+wsum[1]+wsum[2]+wsum[3]+wsum[4];
        float iT = 1.0f / T;           // psf ~= (za/T)(yb/T)(xc), T = sum(psf)
        for (int a=0;a<5;++a) wz[a] = wsum[a]   * iT;
        for (int b=0;b<5;++b) wy[b] = wsum[5+b] * iT;
        for (int c=0;c<5;++c) wx[c] = wsum[10+c];
    }
    __syncthreads();

    const int s  = blockIdx.x;
    const int y0 = blockIdx.y * CH;
    const int stride = *stride_p;
    const int z = s * stride;

    // prefill ring slots for rows y0-2 .. y0+1
    for (int p = 0; p < 4; ++p) {
        int yy = y0 - 2 + p;
        __syncthreads();
        bool yin = (yy >= 0) && (yy < HH);
        #pragma unroll
        for (int a = 0; a < 5; ++a) {
            int zz = z + a - 2;
            bool ok = yin && (zz >= 0) && (zz < DD);
            raw[a][2 + t] = ok ? x[zz*HWW + yy*WW + t] : 0.f;
        }
        __syncthreads();
        int slot = (yy + 10) % 5;
        #pragma unroll
        for (int a = 0; a < 5; ++a) {
            float acc = 0.f;
            #pragma unroll
            for (int c = 0; c < 5; ++c) acc = fmaf(wx[c], raw[a][t + c], acc);
            cx[a][slot][t] = acc;
        }
    }

    for (int y = y0; y < y0 + CH; ++y) {
        int yy = y + 2;
        __syncthreads();                               // ring-overwrite guard
        bool yin = (yy < HH);
        #pragma unroll
        for (int a = 0; a < 5; ++a) {
            int zz = z + a - 2;
            bool ok = yin && (zz >= 0) && (zz < DD);
            raw[a][2 + t] = ok ? x[zz*HWW + yy*WW + t] : 0.f;
        }
        __syncthreads();
        int slot = (yy + 10) % 5;
        #pragma unroll
        for (int a = 0; a < 5; ++a) {
            float acc = 0.f;
            #pragma unroll
            for (int c = 0; c < 5; ++c) acc = fmaf(wx[c], raw[a][t + c], acc);
            cx[a][slot][t] = acc;
        }
        __syncthreads();
        float g = 0.f;
        #pragma unroll
        for (int a = 0; a < 5; ++a) {
            float ty = 0.f;
            #pragma unroll
            for (int b = 0; b < 5; ++b) {
                int sl = (y + b - 2 + 10) % 5;
                ty = fmaf(wy[b], cx[a][sl][t], ty);
            }
            g = fmaf(wz[a], ty, g);
        }
        int o = s*HWW + y*WW + t;
        err[o] = g - slices[o];
    }
}

// ---------------------------------------------------------------------------
// K2: x_out = x - ALPHA*( At(err) + BETA*dR(x) ), optional final relu.
// At uses flipped separable factors. Block: (z, y-chunk); per y-step stages
// 3 x-rows (reg ring, 3z x 3y) + <=3 err rows (x-convolved into 5-y ring).
// ---------------------------------------------------------------------------
__global__ __launch_bounds__(192) void srr_upd_k(
    const float* __restrict__ x, const float* __restrict__ err,
    const float* __restrict__ psf, const int* __restrict__ stride_p,
    float* __restrict__ xout, int n_slices, int apply_relu)
{
    __shared__ float spsf[128];
    __shared__ float wzf[5], wyf[5], wxf[5], wsum[16];
    __shared__ float xr[3][3][200];        // raw x rows [z-off][y-ring][2+x]
    __shared__ float eraw[NSMAX][200];     // raw err rows (halo 2)
    __shared__ float ecx[NSMAX][5][192];   // x-convolved err rows [slice][y-ring][x]
    __shared__ int   s_cnt;
    __shared__ int   s_idx[NSMAX];
    __shared__ float s_wz[NSMAX];

    const int t = threadIdx.x;
    if (t < 125) spsf[t] = psf[t];
    if (t >= 128 && t < 176) {             // zero halos: 9 xr rows + 3 eraw rows
        int q = t - 128, row = q >> 2, p = q & 3;
        int col = (p < 2) ? p : (192 + p);
        if (row < 9) xr[row/3][row%3][col] = 0.f;
        else         eraw[row-9][col] = 0.f;
    }
    __syncthreads();
    if (t < 5)               { float s=0; for (int k=0;k<25;++k) s+=spsf[t*25+k]; wsum[t]=s; }
    else if (t>=8 && t<13)   { int b=t-8;  float s=0; for(int a=0;a<5;++a) for(int c=0;c<5;++c) s+=spsf[a*25+b*5+c]; wsum[t-3]=s; }
    else if (t>=16 && t<21)  { int c=t-16; float s=0; for(int a=0;a<5;++a) for(int b=0;b<5;++b) s+=spsf[a*25+b*5+c]; wsum[t-6]=s; }
    __syncthreads();
    const int z = blockIdx.x;
    if (t == 0) {
        float T = wsum[0]+wsum[1]+wsum[2]+wsum[3]+wsum[4];
        float iT = 1.0f / T;
        for (int a=0;a<5;++a) wzf[a] = wsum[4-a]      * iT;   // flipped
        for (int b=0;b<5;++b) wyf[b] = wsum[5+(4-b)]  * iT;
        for (int c=0;c<5;++c) wxf[c] = wsum[10+(4-c)];
        int stride = *stride_p;
        int cnt = 0;
        for (int a = 0; a < 5; ++a) {       // which err slices touch plane z
            int zz = z + a - 2;
            if (zz >= 0 && zz < DD && (zz % stride) == 0) {
                int ss = zz / stride;
                if (ss < n_slices && cnt < NSMAX) { s_idx[cnt]=ss; s_wz[cnt]=wzf[a]; ++cnt; }
            }
        }
        s_cnt = cnt;
    }
    __syncthreads();
    const int y0  = blockIdx.y * CH;
    const int cnt = s_cnt;

    // prefill: ecx rows y0-2..y0+1, xr rows y0-1..y0
    for (int p = 0; p < 4; ++p) {
        int yy = y0 - 2 + p;
        __syncthreads();
        bool yin = (yy >= 0) && (yy < HH);
        for (int j = 0; j < cnt; ++j)
            eraw[j][2 + t] = yin ? err[s_idx[j]*HWW + yy*WW + t] : 0.f;
        if (p == 1 || p == 2) {
            #pragma unroll
            for (int zo = 0; zo < 3; ++zo) {
                int zz = z + zo - 1;
                bool ok = yin && zz >= 0 && zz < DD;
                xr[zo][(yy + 3) % 3][2 + t] = ok ? x[zz*HWW + yy*WW + t] : 0.f;
            }
        }
        __syncthreads();
        int slot = (yy + 10) % 5;
        for (int j = 0; j < cnt; ++j) {
            float acc = 0.f;
            #pragma unroll
            for (int c = 0; c < 5; ++c) acc = fmaf(wxf[c], eraw[j][t + c], acc);
            ecx[j][slot][t] = acc;
        }
    }

    for (int y = y0; y < y0 + CH; ++y) {
        __syncthreads();                               // ring-overwrite guard
        {
            int yy = y + 2;
            bool yin = (yy < HH);
            for (int j = 0; j < cnt; ++j)
                eraw[j][2 + t] = yin ? err[s_idx[j]*HWW + yy*WW + t] : 0.f;
            int y1 = y + 1;
            bool y1in = (y1 < HH);
            #pragma unroll
            for (int zo = 0; zo < 3; ++zo) {
                int zz = z + zo - 1;
                bool ok = y1in && zz >= 0 && zz < DD;
                xr[zo][(y1 + 3) % 3][2 + t] = ok ? x[zz*HWW + y1*WW + t] : 0.f;
            }
        }
        __syncthreads();
        {
            int slot = (y + 12) % 5;
            for (int j = 0; j < cnt; ++j) {
                float acc = 0.f;
                #pragma unroll
                for (int c = 0; c < 5; ++c) acc = fmaf(wxf[c], eraw[j][t + c], acc);
                ecx[j][slot][t] = acc;
            }
        }
        __syncthreads();
        // data term
        float g = 0.f;
        for (int j = 0; j < cnt; ++j) {
            float ty = 0.f;
            #pragma unroll
            for (int b = 0; b < 5; ++b) {
                int sl = (y + b - 2 + 10) % 5;
                ty = fmaf(wyf[b], ecx[j][sl][t], ty);
            }
            g = fmaf(s_wz[j], ty, g);
        }
        // regularizer (zero on 1-voxel border)
        const float v0 = xr[1][(y + 3) % 3][2 + t];
        float reg = 0.f;
        if (z >= 1 && z < DD-1 && y >= 1 && y < HH-1 && t >= 1 && t < WW-1) {
            #pragma unroll
            for (int zo = 0; zo < 3; ++zo) {
                #pragma unroll
                for (int dy = -1; dy <= 1; ++dy) {
                    int ys = (y + dy + 3) % 3;
                    #pragma unroll
                    for (int dx = -1; dx <= 1; ++dx) {
                        if (zo == 1 && dy == 0 && dx == 0) continue;
                        float v1 = xr[zo][ys][2 + t + dx];
                        float dv = v0 - v1;
                        int dz = zo - 1;
                        float w = 1.0f / ((float)(dx*dx + dy*dy + dz*dz) * (DELTA*DELTA));
                        float dvw = dv * w;
                        reg = fmaf(dvw, rsqrtf(fmaf(dv, dvw, 1.0f)), reg);
                    }
                }
            }
        }
        float xn = v0 - ALPHA * (g + BETA * reg);
        if (apply_relu) xn = fmaxf(xn, 0.f);
        xout[z*HWW + y*WW + t] = xn;
    }
}

extern "C" void kernel_launch(void* const* d_in, const int* in_sizes, int n_in,
                              void* d_out, int out_size, void* d_ws, size_t ws_size,
                              hipStream_t stream) {
    // inputs: 0=theta (unused), 1=slices, 2=volume, 3=psf, 4=stride
    const float* slices = (const float*)d_in[1];
    const float* volume = (const float*)d_in[2];
    const float* psf    = (const float*)d_in[3];
    const int*   strd   = (const int*)d_in[4];

    const int n_slices = in_sizes[1] / (HH * WW);   // 96

    float* x_ws  = (float*)d_ws;                    // 192^3 floats
    float* err   = x_ws + (size_t)DD * HH * WW;     // n_slices*H*W floats
    float* x_out = (float*)d_out;                   // pong buffer / final output

    dim3 blk(WW, 1, 1);
    dim3 gA(n_slices, HH / CH);   // 96 x 8
    dim3 gB(DD, HH / CH);         // 192 x 8

    const float* src = volume;
    for (int it = 0; it < N_ITER; ++it) {
        float* dst = (it & 1) ? x_out : x_ws;
        srr_err_k<<<gA, blk, 0, stream>>>(src, slices, psf, strd, err, n_slices);
        srr_upd_k<<<gB, blk, 0, stream>>>(src, err, psf, strd, dst, n_slices,
                                          (it == N_ITER - 1) ? 1 : 0);
        src = dst;
    }
}

// Round 3
// 1080.351 us; speedup vs baseline: 3.9276x; 1.6052x over previous
//
#include <hip/hip_runtime.h>
#include <math.h>

#define ALPHA 0.5f
#define BETA  2.0e-4f   // 0.02 * 0.1 * 0.1
#define DELTA 0.1f
#define N_ITER 10

#define DD 192
#define HH 192
#define WW 192
#define HWW (192*192)
#define CH 16          // y-rows produced per block
#define NSMAX 4        // staged err slices per z-pair (stride>=2 -> <=3)

// robust-TV single-neighbor term: acc += dv*w / sqrt(1 + dv*dv*w)
#define RT(v1, Wc) do { float dv_ = v0 - (v1); float dw_ = dv_ * (Wc);            \
    acc = fmaf(dw_, rsqrtf(fmaf(dv_, dw_, 1.0f)), acc); } while (0)

// 26 neighbors for an output on center plane pb (pa=z-1, pc=z+1 LDS/delay idx)
#define REG26(pa, pb, pc)                                                          \
    RT(nbm[pa][0], W3); RT(m[pa][0], W2); RT(nbp[pa][0], W3);                      \
    RT(nbm[pa][1], W2); RT(m[pa][1], W1); RT(nbp[pa][1], W2);                      \
    RT(nbm[pa][2], W3); RT(m[pa][2], W2); RT(nbp[pa][2], W3);                      \
    RT(nbm[pb][0], W2); RT(m[pb][0], W1); RT(nbp[pb][0], W2);                      \
    RT(nbm[pb][1], W1);                   RT(nbp[pb][1], W1);                      \
    RT(nbm[pb][2], W2); RT(m[pb][2], W1); RT(nbp[pb][2], W2);                      \
    RT(nbm[pc][0], W3); RT(m[pc][0], W2); RT(nbp[pc][0], W3);                      \
    RT(nbm[pc][1], W2); RT(m[pc][1], W1); RT(nbp[pc][1], W2);                      \
    RT(nbm[pc][2], W3); RT(m[pc][2], W2); RT(nbp[pc][2], W3);

// ---------------------------------------------------------------------------
// K1: err[s,y,x] = conv3(x,psf)[s*stride,y,x] - slices[s,y,x]
// Register y-pipeline: per step stage one x-row for 5 z-planes, x-conv +
// z-combine in regs, update 5 pending y-accumulators. One barrier/step,
// 2-slot LDS ring, global prefetch overlapped with compute.
// ---------------------------------------------------------------------------
__global__ __launch_bounds__(192) void srr_err_k(
    const float* __restrict__ x, const float* __restrict__ slices,
    const float* __restrict__ psf, const int* __restrict__ stride_p,
    float* __restrict__ err, int n_slices)
{
    __shared__ float spsf[125];
    __shared__ float wsum[16];
    __shared__ float wzs[5], wys[5], wxs[5];
    __shared__ float raw[5][2][200];   // [plane][slot][2+x], halos stay 0

    const int t = threadIdx.x;
    if (t < 125) spsf[t] = psf[t];
    if (t >= 128 && t < 168) {         // zero 4 halo cols of 5x2 rows
        int q = t - 128, plane = q >> 3, r = q & 7;
        int slq = r >> 2, p = r & 3;
        raw[plane][slq][(p < 2) ? p : (192 + p)] = 0.f;
    }
    __syncthreads();
    if (t < 5)               { float s=0; for (int k=0;k<25;++k) s+=spsf[t*25+k]; wsum[t]=s; }
    else if (t>=8 && t<13)   { int b=t-8;  float s=0; for(int a=0;a<5;++a) for(int c=0;c<5;++c) s+=spsf[a*25+b*5+c]; wsum[t-3]=s; }
    else if (t>=16 && t<21)  { int c=t-16; float s=0; for(int a=0;a<5;++a) for(int b=0;b<5;++b) s+=spsf[a*25+b*5+c]; wsum[t-6]=s; }
    __syncthreads();
    if (t == 0) {
        float T = wsum[0]+wsum[1]+wsum[2]+wsum[3]+wsum[4];
        float iT = 1.0f / T;
        for (int a=0;a<5;++a) wzs[a] = wsum[a]   * iT;
        for (int b=0;b<5;++b) wys[b] = wsum[5+b] * iT;
        for (int c=0;c<5;++c) wxs[c] = wsum[10+c];
    }
    __syncthreads();

    const int s  = blockIdx.x;
    const int y0 = blockIdx.y * CH;
    const int stride = *stride_p;
    const int z = s * stride;

    float wzr[5], wyr[5], wxr[5];
    #pragma unroll
    for (int i = 0; i < 5; ++i) { wzr[i]=wzs[i]; wyr[i]=wys[i]; wxr[i]=wxs[i]; }

    const float* xp[5];
    bool okp[5];
    #pragma unroll
    for (int a = 0; a < 5; ++a) {
        int zz = z + a - 2;
        okp[a] = (zz >= 0) && (zz < DD);
        xp[a] = x + (size_t)(okp[a] ? zz : 0) * HWW + (ptrdiff_t)(y0 - 2) * WW + t;
    }
    const float* spm = slices + (size_t)s * HWW + (size_t)y0 * WW + t;
    float*       epo = err    + (size_t)s * HWW + (size_t)y0 * WW + t;

    float xv[5];
    {
        bool yg = (y0 - 2 >= 0);
        #pragma unroll
        for (int a = 0; a < 5; ++a) { xv[a] = (okp[a] && yg) ? *xp[a] : 0.f; xp[a] += WW; }
    }
    float P[5] = {0.f, 0.f, 0.f, 0.f, 0.f};
    float sv = 0.f, svn = 0.f;

    for (int step = 0; step < CH + 4; ++step) {
        const int yy = y0 - 2 + step;
        const int sl = (yy + 4) & 1;
        #pragma unroll
        for (int a = 0; a < 5; ++a) raw[a][sl][2 + t] = xv[a];
        __syncthreads();
        {   // prefetch next row + next slices row (overlaps compute below)
            int yn = yy + 1;
            bool yg = (yn >= 0) && (yn < HH);
            #pragma unroll
            for (int a = 0; a < 5; ++a) { xv[a] = (okp[a] && yg) ? *xp[a] : 0.f; xp[a] += WW; }
            int yv = yy - 1;
            if (yv >= y0 && yv < y0 + CH) { svn = *spm; spm += WW; } else svn = 0.f;
        }
        float cxz = 0.f;
        #pragma unroll
        for (int a = 0; a < 5; ++a) {
            float c4 = 0.f;
            #pragma unroll
            for (int c = 0; c < 5; ++c) c4 = fmaf(wxr[c], raw[a][sl][t + c], c4);
            cxz = fmaf(wzr[a], c4, cxz);
        }
        P[0] = fmaf(wyr[4], cxz, P[0]);
        P[1] = fmaf(wyr[3], cxz, P[1]);
        P[2] = fmaf(wyr[2], cxz, P[2]);
        P[3] = fmaf(wyr[1], cxz, P[3]);
        P[4] = fmaf(wyr[0], cxz, P[4]);
        if (yy - 2 >= y0) { *epo = P[0] - sv; epo += WW; }
        sv = svn;
        P[0]=P[1]; P[1]=P[2]; P[2]=P[3]; P[3]=P[4]; P[4]=0.f;
    }
}

// ---------------------------------------------------------------------------
// K2: x_out = x - ALPHA*( At(err) + BETA*dR(x) ), optional final relu.
// z-pair blocking: planes (2p, 2p+1) share staged err slices + their x-conv
// and 4-plane x staging. Register y-pipelines for the y-conv; 4x3 register
// delay line gives dx=0 reg-term neighbors; dx=+-1 from LDS ring (depth 4).
// One barrier/step, prefetch overlapped.
// ---------------------------------------------------------------------------
__global__ __launch_bounds__(192) void srr_upd_k(
    const float* __restrict__ x, const float* __restrict__ err,
    const float* __restrict__ psf, const int* __restrict__ stride_p,
    float* __restrict__ xout, int n_slices, int apply_relu)
{
    __shared__ float spsf[125];
    __shared__ float wsum[16];
    __shared__ float wzs[5], wys[5], wxs[5];   // flipped factors
    __shared__ float xr[4][4][200];            // [plane][row-slot][2+x]
    __shared__ float eraw[NSMAX][2][200];      // [slice][slot][2+x]
    __shared__ int   s_cnt;
    __shared__ int   s_sidx[NSMAX];
    __shared__ float s_w0[NSMAX], s_w1[NSMAX];

    const int t = threadIdx.x;
    if (t < 125) spsf[t] = psf[t];
    if (t >= 96 && t < 192) {                  // zero halo cols (16+8 rows x 4)
        int q = t - 96, row = q >> 2, p = q & 3;
        int col = (p < 2) ? p : (192 + p);
        if (row < 16) xr[row >> 2][row & 3][col] = 0.f;
        else { int r = row - 16; eraw[r >> 1][r & 1][col] = 0.f; }
    }
    __syncthreads();
    if (t < 5)               { float s=0; for (int k=0;k<25;++k) s+=spsf[t*25+k]; wsum[t]=s; }
    else if (t>=8 && t<13)   { int b=t-8;  float s=0; for(int a=0;a<5;++a) for(int c=0;c<5;++c) s+=spsf[a*25+b*5+c]; wsum[t-3]=s; }
    else if (t>=16 && t<21)  { int c=t-16; float s=0; for(int a=0;a<5;++a) for(int b=0;b<5;++b) s+=spsf[a*25+b*5+c]; wsum[t-6]=s; }
    __syncthreads();
    const int pz = blockIdx.x;
    const int z0 = 2 * pz;
    if (t == 0) {
        float T = wsum[0]+wsum[1]+wsum[2]+wsum[3]+wsum[4];
        float iT = 1.0f / T;
        for (int a=0;a<5;++a) wzs[a] = wsum[4-a]        * iT;  // flipped
        for (int b=0;b<5;++b) wys[b] = wsum[5+(4-b)]    * iT;
        for (int c=0;c<5;++c) wxs[c] = wsum[10+(4-c)];
        int stride = *stride_p;
        int cnt = 0;
        for (int a = 0; a < 6; ++a) {          // err planes z0-2 .. z0+3
            int zz = z0 + a - 2;
            if (zz >= 0 && zz < DD && (zz % stride) == 0) {
                int ss = zz / stride;
                if (ss < n_slices && cnt < NSMAX) {
                    s_sidx[cnt] = ss;
                    s_w0[cnt] = (a <= 4) ? wzs[a]     : 0.f;   // weight for z0
                    s_w1[cnt] = (a >= 1) ? wzs[a - 1] : 0.f;   // weight for z0+1
                    ++cnt;
                }
            }
        }
        s_cnt = cnt;
    }
    __syncthreads();

    const int y0  = blockIdx.y * CH;
    const int cnt = s_cnt;

    float wyr[5], wxr[5];
    #pragma unroll
    for (int i = 0; i < 5; ++i) { wyr[i] = wys[i]; wxr[i] = wxs[i]; }
    float w0r[NSMAX], w1r[NSMAX];
    const float* ep[NSMAX];
    #pragma unroll
    for (int j = 0; j < NSMAX; ++j) {
        bool v = (j < cnt);
        w0r[j] = v ? s_w0[j] : 0.f;
        w1r[j] = v ? s_w1[j] : 0.f;
        ep[j] = err + (size_t)(v ? s_sidx[j] : 0) * HWW + (ptrdiff_t)(y0 - 2) * WW + t;
    }
    const float* xp[4];
    bool okp[4];
    #pragma unroll
    for (int zo = 0; zo < 4; ++zo) {
        int zz = z0 - 1 + zo;
        okp[zo] = (zz >= 0) && (zz < DD);
        xp[zo] = x + (size_t)(okp[zo] ? zz : 0) * HWW + (ptrdiff_t)(y0 - 2) * WW + t;
    }
    float* op0 = xout + (size_t)z0 * HWW       + (size_t)y0 * WW + t;
    float* op1 = xout + (size_t)(z0 + 1) * HWW + (size_t)y0 * WW + t;
    const bool okz0 = (z0 >= 1);
    const bool okz1 = (z0 + 1 <= DD - 2);
    const bool tok  = (t >= 1) && (t <= WW - 2);

    float xv[4], ev[NSMAX];
    {
        bool yg = (y0 - 2 >= 0);
        #pragma unroll
        for (int zo = 0; zo < 4; ++zo) { xv[zo] = (okp[zo] && yg) ? *xp[zo] : 0.f; xp[zo] += WW; }
        #pragma unroll
        for (int j = 0; j < NSMAX; ++j) { ev[j] = (j < cnt && yg) ? *ep[j] : 0.f; ep[j] += WW; }
    }
    float m[4][3];
    #pragma unroll
    for (int zo = 0; zo < 4; ++zo) { m[zo][0]=0.f; m[zo][1]=0.f; m[zo][2]=0.f; }
    float Pd0[5] = {0.f,0.f,0.f,0.f,0.f};
    float Pd1[5] = {0.f,0.f,0.f,0.f,0.f};
    float rr0 = 0.f, rr1 = 0.f;

    const float W1 = 1.0f / (1.0f * DELTA * DELTA);
    const float W2 = 1.0f / (2.0f * DELTA * DELTA);
    const float W3 = 1.0f / (3.0f * DELTA * DELTA);

    for (int step = 0; step < CH + 4; ++step) {
        const int yy  = y0 - 2 + step;
        const int sl4 = (yy + 4) & 3;
        const int sl2 = (yy + 4) & 1;
        #pragma unroll
        for (int zo = 0; zo < 4; ++zo) xr[zo][sl4][2 + t] = xv[zo];
        #pragma unroll
        for (int j = 0; j < NSMAX; ++j) if (j < cnt) eraw[j][sl2][2 + t] = ev[j];
        __syncthreads();
        // delay-line shift (row yy) BEFORE xv is overwritten by prefetch
        #pragma unroll
        for (int zo = 0; zo < 4; ++zo) { m[zo][0]=m[zo][1]; m[zo][1]=m[zo][2]; m[zo][2]=xv[zo]; }
        {   // prefetch row yy+1 (overlaps all compute below)
            int yn = yy + 1;
            bool yg = (yn >= 0) && (yn < HH);
            #pragma unroll
            for (int zo = 0; zo < 4; ++zo) { xv[zo] = (okp[zo] && yg) ? *xp[zo] : 0.f; xp[zo] += WW; }
            #pragma unroll
            for (int j = 0; j < NSMAX; ++j) { if (j < cnt) { ev[j] = yg ? *ep[j] : 0.f; ep[j] += WW; } }
        }
        // data term: shared x-conv of err rows, two z-weight combos
        float e0 = 0.f, e1 = 0.f;
        #pragma unroll
        for (int j = 0; j < NSMAX; ++j) {
            if (j < cnt) {
                float ex = 0.f;
                #pragma unroll
                for (int c = 0; c < 5; ++c) ex = fmaf(wxr[c], eraw[j][sl2][t + c], ex);
                e0 = fmaf(w0r[j], ex, e0);
                e1 = fmaf(w1r[j], ex, e1);
            }
        }
        Pd0[0]=fmaf(wyr[4],e0,Pd0[0]); Pd0[1]=fmaf(wyr[3],e0,Pd0[1]); Pd0[2]=fmaf(wyr[2],e0,Pd0[2]);
        Pd0[3]=fmaf(wyr[1],e0,Pd0[3]); Pd0[4]=fmaf(wyr[0],e0,Pd0[4]);
        Pd1[0]=fmaf(wyr[4],e1,Pd1[0]); Pd1[1]=fmaf(wyr[3],e1,Pd1[1]); Pd1[2]=fmaf(wyr[2],e1,Pd1[2]);
        Pd1[3]=fmaf(wyr[1],e1,Pd1[3]); Pd1[4]=fmaf(wyr[0],e1,Pd1[4]);
        // store y_s = yy-2 (uses rr from previous step)
        if (yy - 2 >= y0) {
            float o0 = m[1][0] - ALPHA * (Pd0[0] + BETA * rr0);
            float o1 = m[2][0] - ALPHA * (Pd1[0] + BETA * rr1);
            if (apply_relu) { o0 = fmaxf(o0, 0.f); o1 = fmaxf(o1, 0.f); }
            *op0 = o0; op0 += WW;
            *op1 = o1; op1 += WW;
        }
        // regularizer for y_r = yy-1 (consumed next step)
        const int yr = yy - 1;
        if (yr >= y0 && yr < y0 + CH) {
            const bool oky = (yr >= 1) && (yr <= HH - 2);
            const int rs0 = (yy + 2) & 3, rs1 = (yy + 3) & 3, rs2 = (yy + 4) & 3;
            float nbm[4][3], nbp[4][3];
            #pragma unroll
            for (int zo = 0; zo < 4; ++zo) {
                nbm[zo][0] = xr[zo][rs0][1 + t]; nbp[zo][0] = xr[zo][rs0][3 + t];
                nbm[zo][1] = xr[zo][rs1][1 + t]; nbp[zo][1] = xr[zo][rs1][3 + t];
                nbm[zo][2] = xr[zo][rs2][1 + t]; nbp[zo][2] = xr[zo][rs2][3 + t];
            }
            {
                float v0 = m[1][1]; float acc = 0.f;
                REG26(0, 1, 2);
                rr0 = (okz0 && oky && tok) ? acc : 0.f;
            }
            {
                float v0 = m[2][1]; float acc = 0.f;
                REG26(1, 2, 3);
                rr1 = (okz1 && oky && tok) ? acc : 0.f;
            }
        } else { rr0 = 0.f; rr1 = 0.f; }
        // shift y-pipelines
        Pd0[0]=Pd0[1]; Pd0[1]=Pd0[2]; Pd0[2]=Pd0[3]; Pd0[3]=Pd0[4]; Pd0[4]=0.f;
        Pd1[0]=Pd1[1]; Pd1[1]=Pd1[2]; Pd1[2]=Pd1[3]; Pd1[3]=Pd1[4]; Pd1[4]=0.f;
    }
}

extern "C" void kernel_launch(void* const* d_in, const int* in_sizes, int n_in,
                              void* d_out, int out_size, void* d_ws, size_t ws_size,
                              hipStream_t stream) {
    // inputs: 0=theta (unused), 1=slices, 2=volume, 3=psf, 4=stride
    const float* slices = (const float*)d_in[1];
    const float* volume = (const float*)d_in[2];
    const float* psf    = (const float*)d_in[3];
    const int*   strd   = (const int*)d_in[4];

    const int n_slices = in_sizes[1] / (HH * WW);   // 96

    float* x_ws  = (float*)d_ws;                    // 192^3 floats
    float* err   = x_ws + (size_t)DD * HH * WW;     // n_slices*H*W floats
    float* x_out = (float*)d_out;                   // pong buffer / final output

    dim3 blk(WW, 1, 1);
    dim3 gA(n_slices, HH / CH);    // 96 x 12
    dim3 gB(DD / 2,   HH / CH);    // 96 x 12

    const float* src = volume;
    for (int it = 0; it < N_ITER; ++it) {
        float* dst = (it & 1) ? x_out : x_ws;
        srr_err_k<<<gA, blk, 0, stream>>>(src, slices, psf, strd, err, n_slices);
        srr_upd_k<<<gB, blk, 0, stream>>>(src, err, psf, strd, dst, n_slices,
                                          (it == N_ITER - 1) ? 1 : 0);
        src = dst;
    }
}

// Round 4
// 991.218 us; speedup vs baseline: 4.2808x; 1.0899x over previous
//
#include <hip/hip_runtime.h>
#include <math.h>

#define ALPHA 0.5f
#define BETA  2.0e-4f   // 0.02 * 0.1 * 0.1
#define DELTA 0.1f
#define N_ITER 10

#define DD 192
#define HH 192
#define WW 192
#define HWW (192*192)
#define CHE 16         // err kernel: y-rows per block
#define CHU 12         // upd kernel: y-rows per block
#define NSMAX 4        // err slices touching a z-pair window (stride>=2 -> <=3)

// robust-TV single-neighbor term: acc += dv*w / sqrt(1 + dv*dv*w)
#define RT(v1, Wc) do { float dv_ = v0 - (v1); float dw_ = dv_ * (Wc);            \
    acc = fmaf(dw_, rsqrtf(fmaf(dv_, dw_, 1.0f)), acc); } while (0)

// 26 neighbors for an output on center plane pb (pa=z-1, pc=z+1 delay idx)
#define REG26(pa, pb, pc)                                                          \
    RT(nbm[pa][0], W3); RT(m[pa][0], W2); RT(nbp[pa][0], W3);                      \
    RT(nbm[pa][1], W2); RT(m[pa][1], W1); RT(nbp[pa][1], W2);                      \
    RT(nbm[pa][2], W3); RT(m[pa][2], W2); RT(nbp[pa][2], W3);                      \
    RT(nbm[pb][0], W2); RT(m[pb][0], W1); RT(nbp[pb][0], W2);                      \
    RT(nbm[pb][1], W1);                   RT(nbp[pb][1], W1);                      \
    RT(nbm[pb][2], W2); RT(m[pb][2], W1); RT(nbp[pb][2], W2);                      \
    RT(nbm[pc][0], W3); RT(m[pc][0], W2); RT(nbp[pc][0], W3);                      \
    RT(nbm[pc][1], W2); RT(m[pc][1], W1); RT(nbp[pc][1], W2);                      \
    RT(nbm[pc][2], W3); RT(m[pc][2], W2); RT(nbp[pc][2], W3);

// ---------------------------------------------------------------------------
// K1: err_xy[s] = conv_x(conv_y( A(x)[s] - slices[s], wy_flip ), wx_flip)
// Two chained register y-pipelines: P (forward wy) produces err rows; each
// err row is staged in LDS, x-convolved with flipped wx, and fed into Q
// (flipped wy) which produces err_xy rows. One barrier/step.
// ---------------------------------------------------------------------------
__global__ __launch_bounds__(192) void srr_err_k(
    const float* __restrict__ x, const float* __restrict__ slices,
    const float* __restrict__ psf, const int* __restrict__ stride_p,
    float* __restrict__ err_xy, int n_slices)
{
    __shared__ float spsf[125];
    __shared__ float wsum[16];
    __shared__ float wzs[5], wys[5], wxs[5];
    __shared__ float raw[5][2][200];   // raw x rows [plane][slot][2+x], halos 0
    __shared__ float erw[2][200];      // err rows [slot][2+x], halos 0

    const int t = threadIdx.x;
    if (t < 125) spsf[t] = psf[t];
    if (t >= 128 && t < 176) {         // zero halo cols: 10 raw rows + 2 erw rows
        int q = t - 128, row = q >> 2, p = q & 3;
        int col = (p < 2) ? p : (192 + p);
        if (row < 10) raw[row >> 1][row & 1][col] = 0.f;
        else          erw[row - 10][col] = 0.f;
    }
    __syncthreads();
    if (t < 5)               { float s=0; for (int k=0;k<25;++k) s+=spsf[t*25+k]; wsum[t]=s; }
    else if (t>=8 && t<13)   { int b=t-8;  float s=0; for(int a=0;a<5;++a) for(int c=0;c<5;++c) s+=spsf[a*25+b*5+c]; wsum[t-3]=s; }
    else if (t>=16 && t<21)  { int c=t-16; float s=0; for(int a=0;a<5;++a) for(int b=0;b<5;++b) s+=spsf[a*25+b*5+c]; wsum[t-6]=s; }
    __syncthreads();
    if (t == 0) {
        float T = wsum[0]+wsum[1]+wsum[2]+wsum[3]+wsum[4];
        float iT = 1.0f / T;
        for (int a=0;a<5;++a) wzs[a] = wsum[a]   * iT;
        for (int b=0;b<5;++b) wys[b] = wsum[5+b] * iT;
        for (int c=0;c<5;++c) wxs[c] = wsum[10+c];
    }
    __syncthreads();

    const int s  = blockIdx.x;
    const int y0 = blockIdx.y * CHE;
    const int stride = *stride_p;
    const int z = s * stride;

    float wzr[5], wyr[5], wxr[5], wyf[5], wxf[5];
    #pragma unroll
    for (int i = 0; i < 5; ++i) {
        wzr[i]=wzs[i]; wyr[i]=wys[i]; wxr[i]=wxs[i];
        wyf[i]=wys[4-i]; wxf[i]=wxs[4-i];          // flipped for the adjoint
    }

    const float* xp[5]; bool okp[5];
    #pragma unroll
    for (int a = 0; a < 5; ++a) {
        int zz = z + a - 2;
        okp[a] = (zz >= 0) && (zz < DD);
        xp[a] = x + (size_t)(okp[a] ? zz : 0) * HWW + (ptrdiff_t)(y0 - 4) * WW + t;
    }
    const float* spm = slices + (size_t)s * HWW + (ptrdiff_t)(y0 - 2) * WW + t;
    float*       epo = err_xy + (size_t)s * HWW + (size_t)y0 * WW + t;

    float xv[5];
    {
        bool yg = (y0 - 4 >= 0);
        #pragma unroll
        for (int a = 0; a < 5; ++a) { xv[a] = (okp[a] && yg) ? *xp[a] : 0.f; xp[a] += WW; }
    }
    float P[5] = {0.f,0.f,0.f,0.f,0.f};
    float Q[5] = {0.f,0.f,0.f,0.f,0.f};
    float er_prev = 0.f, sv = 0.f, svn = 0.f;

    for (int k = 0; k < CHE + 9; ++k) {
        const int yy = y0 - 4 + k;
        const int sl = k & 1;
        #pragma unroll
        for (int a = 0; a < 5; ++a) raw[a][sl][2 + t] = xv[a];
        erw[sl][2 + t] = er_prev;                  // err row (yy-3)
        __syncthreads();
        {   // prefetch x rows (yy+1) + slices row (yy-1); overlaps compute
            int yn = yy + 1;
            bool yg = (yn >= 0) && (yn < HH);
            #pragma unroll
            for (int a = 0; a < 5; ++a) { xv[a] = (okp[a] && yg) ? *xp[a] : 0.f; xp[a] += WW; }
            int yv = yy - 1;
            if (yv >= y0 - 2 && yv < y0 + CHE + 2) {
                svn = (yv >= 0 && yv < HH) ? *spm : 0.f;
                spm += WW;
            } else svn = 0.f;
        }
        // forward: A(x) row yy
        float cxz = 0.f;
        #pragma unroll
        for (int a = 0; a < 5; ++a) {
            float c4 = 0.f;
            #pragma unroll
            for (int c = 0; c < 5; ++c) c4 = fmaf(wxr[c], raw[a][sl][t + c], c4);
            cxz = fmaf(wzr[a], c4, cxz);
        }
        P[0]=fmaf(wyr[4],cxz,P[0]); P[1]=fmaf(wyr[3],cxz,P[1]); P[2]=fmaf(wyr[2],cxz,P[2]);
        P[3]=fmaf(wyr[1],cxz,P[3]); P[4]=fmaf(wyr[0],cxz,P[4]);
        {   // finalize err row (yy-2), staged next step
            int yr = yy - 2;
            er_prev = (yr >= 0 && yr < HH) ? (P[0] - sv) : 0.f;
        }
        sv = svn;
        // adjoint xy: x-conv staged err row (yy-3), flipped weights
        float ex = 0.f;
        #pragma unroll
        for (int c = 0; c < 5; ++c) ex = fmaf(wxf[c], erw[sl][t + c], ex);
        Q[0]=fmaf(wyf[4],ex,Q[0]); Q[1]=fmaf(wyf[3],ex,Q[1]); Q[2]=fmaf(wyf[2],ex,Q[2]);
        Q[3]=fmaf(wyf[1],ex,Q[3]); Q[4]=fmaf(wyf[0],ex,Q[4]);
        {   // store err_xy row (yy-5)
            int yq = yy - 5;
            if (yq >= y0) { *epo = Q[0]; epo += WW; }
        }
        P[0]=P[1]; P[1]=P[2]; P[2]=P[3]; P[3]=P[4]; P[4]=0.f;
        Q[0]=Q[1]; Q[1]=Q[2]; Q[2]=Q[3]; Q[3]=Q[4]; Q[4]=0.f;
    }
}

// ---------------------------------------------------------------------------
// K2: x_out = x - ALPHA*( At_z(err_xy) + BETA*dR(x) ), optional final relu.
// Data term is now just a z-combine of <=3 precomputed err_xy rows (direct
// coalesced global loads, prefetched). z-pair blocking; xr LDS ring only for
// the 26-neighbor reg term; 4x3 register delay line for dx=0 neighbors.
// ---------------------------------------------------------------------------
__global__ __launch_bounds__(192) void srr_upd_k(
    const float* __restrict__ x, const float* __restrict__ err_xy,
    const float* __restrict__ psf, const int* __restrict__ stride_p,
    float* __restrict__ xout, int n_slices, int apply_relu)
{
    __shared__ float spsf[125];
    __shared__ float wsum[8];
    __shared__ float xr[4][4][200];            // [plane][row-slot][2+x]
    __shared__ int   s_cnt, s_sidx[NSMAX];
    __shared__ float s_w0[NSMAX], s_w1[NSMAX];

    const int t = threadIdx.x;
    if (t < 125) spsf[t] = psf[t];
    if (t >= 128 && t < 192) {                 // zero halo cols of 16 xr rows
        int q = t - 128, row = q >> 2, p = q & 3;
        int col = (p < 2) ? p : (192 + p);
        xr[row >> 2][row & 3][col] = 0.f;
    }
    __syncthreads();
    if (t < 5) { float s=0; for (int k=0;k<25;++k) s+=spsf[t*25+k]; wsum[t]=s; }
    __syncthreads();
    const int z0 = 2 * blockIdx.x;
    if (t == 0) {
        float T = wsum[0]+wsum[1]+wsum[2]+wsum[3]+wsum[4];
        float iT = 1.0f / T;
        float wzf[5];
        for (int a=0;a<5;++a) wzf[a] = wsum[4-a] * iT;   // flipped z weights
        int stride = *stride_p;
        int cnt = 0;
        for (int d = -2; d <= 3; ++d) {        // err planes z0-2 .. z0+3
            int zz = z0 + d;
            if (zz >= 0 && zz < DD && (zz % stride) == 0) {
                int ss = zz / stride;
                if (ss < n_slices && cnt < NSMAX) {
                    s_sidx[cnt] = ss;
                    s_w0[cnt] = (d <= 2)  ? wzf[d + 2] : 0.f;   // weight for z0
                    s_w1[cnt] = (d >= -1) ? wzf[d + 1] : 0.f;   // weight for z0+1
                    ++cnt;
                }
            }
        }
        s_cnt = cnt;
    }
    __syncthreads();

    const int y0  = blockIdx.y * CHU;
    const int cnt = s_cnt;

    float w0r[NSMAX], w1r[NSMAX];
    const float* ep[NSMAX];
    #pragma unroll
    for (int j = 0; j < NSMAX; ++j) {
        bool v = (j < cnt);
        w0r[j] = v ? s_w0[j] : 0.f;
        w1r[j] = v ? s_w1[j] : 0.f;
        ep[j] = err_xy + (size_t)(v ? s_sidx[j] : 0) * HWW + (size_t)y0 * WW + t;
    }
    const float* xp[4]; bool okp[4];
    #pragma unroll
    for (int zo = 0; zo < 4; ++zo) {
        int zz = z0 - 1 + zo;
        okp[zo] = (zz >= 0) && (zz < DD);
        xp[zo] = x + (size_t)(okp[zo] ? zz : 0) * HWW + (ptrdiff_t)(y0 - 2) * WW + t;
    }
    float* op0 = xout + (size_t)z0 * HWW       + (size_t)y0 * WW + t;
    float* op1 = xout + (size_t)(z0 + 1) * HWW + (size_t)y0 * WW + t;
    const bool okz0 = (z0 >= 1);
    const bool okz1 = (z0 + 1 <= DD - 2);
    const bool tok  = (t >= 1) && (t <= WW - 2);

    float xv[4];
    {
        bool yg = (y0 - 2 >= 0);
        #pragma unroll
        for (int zo = 0; zo < 4; ++zo) { xv[zo] = (okp[zo] && yg) ? *xp[zo] : 0.f; xp[zo] += WW; }
    }
    float m[4][3];
    #pragma unroll
    for (int zo = 0; zo < 4; ++zo) { m[zo][0]=0.f; m[zo][1]=0.f; m[zo][2]=0.f; }
    float ev[NSMAX], evn[NSMAX];
    #pragma unroll
    for (int j = 0; j < NSMAX; ++j) { ev[j]=0.f; evn[j]=0.f; }
    float rr0 = 0.f, rr1 = 0.f;

    const float W1 = 1.0f / (1.0f * DELTA * DELTA);
    const float W2 = 1.0f / (2.0f * DELTA * DELTA);
    const float W3 = 1.0f / (3.0f * DELTA * DELTA);

    for (int k = 0; k < CHU + 4; ++k) {
        const int yy  = y0 - 2 + k;
        const int sl4 = k & 3;
        #pragma unroll
        for (int zo = 0; zo < 4; ++zo) xr[zo][sl4][2 + t] = xv[zo];
        __syncthreads();
        // delay-line shift (row yy) BEFORE xv is overwritten by prefetch
        #pragma unroll
        for (int zo = 0; zo < 4; ++zo) { m[zo][0]=m[zo][1]; m[zo][1]=m[zo][2]; m[zo][2]=xv[zo]; }
        {   // prefetch x rows (yy+1) and err_xy rows (yy-1); overlaps compute
            int yn = yy + 1;
            bool yg = (yn >= 0) && (yn < HH);
            #pragma unroll
            for (int zo = 0; zo < 4; ++zo) { xv[zo] = (okp[zo] && yg) ? *xp[zo] : 0.f; xp[zo] += WW; }
            int r = yy - 1;
            if (r >= y0 && r < y0 + CHU) {
                #pragma unroll
                for (int j = 0; j < NSMAX; ++j) {
                    if (j < cnt) { evn[j] = *ep[j]; ep[j] += WW; }
                }
            }
        }
        // store y_s = yy-2 (uses ev + rr from previous step)
        if (yy - 2 >= y0) {
            float g0 = 0.f, g1 = 0.f;
            #pragma unroll
            for (int j = 0; j < NSMAX; ++j) {
                g0 = fmaf(w0r[j], ev[j], g0);
                g1 = fmaf(w1r[j], ev[j], g1);
            }
            float o0 = m[1][0] - ALPHA * (g0 + BETA * rr0);
            float o1 = m[2][0] - ALPHA * (g1 + BETA * rr1);
            if (apply_relu) { o0 = fmaxf(o0, 0.f); o1 = fmaxf(o1, 0.f); }
            *op0 = o0; op0 += WW;
            *op1 = o1; op1 += WW;
        }
        #pragma unroll
        for (int j = 0; j < NSMAX; ++j) ev[j] = evn[j];
        // regularizer for y_r = yy-1 (consumed next step)
        const int yr = yy - 1;
        if (yr >= y0 && yr < y0 + CHU) {
            const bool oky = (yr >= 1) && (yr <= HH - 2);
            const int rs0 = (k + 2) & 3, rs1 = (k + 3) & 3, rs2 = k & 3;
            float nbm[4][3], nbp[4][3];
            #pragma unroll
            for (int zo = 0; zo < 4; ++zo) {
                nbm[zo][0] = xr[zo][rs0][1 + t]; nbp[zo][0] = xr[zo][rs0][3 + t];
                nbm[zo][1] = xr[zo][rs1][1 + t]; nbp[zo][1] = xr[zo][rs1][3 + t];
                nbm[zo][2] = xr[zo][rs2][1 + t]; nbp[zo][2] = xr[zo][rs2][3 + t];
            }
            {
                float v0 = m[1][1]; float acc = 0.f;
                REG26(0, 1, 2);
                rr0 = (okz0 && oky && tok) ? acc : 0.f;
            }
            {
                float v0 = m[2][1]; float acc = 0.f;
                REG26(1, 2, 3);
                rr1 = (okz1 && oky && tok) ? acc : 0.f;
            }
        } else { rr0 = 0.f; rr1 = 0.f; }
    }
}

extern "C" void kernel_launch(void* const* d_in, const int* in_sizes, int n_in,
                              void* d_out, int out_size, void* d_ws, size_t ws_size,
                              hipStream_t stream) {
    // inputs: 0=theta (unused), 1=slices, 2=volume, 3=psf, 4=stride
    const float* slices = (const float*)d_in[1];
    const float* volume = (const float*)d_in[2];
    const float* psf    = (const float*)d_in[3];
    const int*   strd   = (const int*)d_in[4];

    const int n_slices = in_sizes[1] / (HH * WW);   // 96

    float* x_ws   = (float*)d_ws;                   // 192^3 floats
    float* err_xy = x_ws + (size_t)DD * HH * WW;    // n_slices*H*W floats
    float* x_out  = (float*)d_out;                  // pong buffer / final output

    dim3 blk(WW, 1, 1);
    dim3 gA(n_slices, HH / CHE);   // 96 x 12
    dim3 gB(DD / 2,   HH / CHU);   // 96 x 16

    const float* src = volume;
    for (int it = 0; it < N_ITER; ++it) {
        float* dst = (it & 1) ? x_out : x_ws;
        srr_err_k<<<gA, blk, 0, stream>>>(src, slices, psf, strd, err_xy, n_slices);
        srr_upd_k<<<gB, blk, 0, stream>>>(src, err_xy, psf, strd, dst, n_slices,
                                          (it == N_ITER - 1) ? 1 : 0);
        src = dst;
    }
}

// Round 6
// 950.914 us; speedup vs baseline: 4.4622x; 1.0424x over previous
//
#include <hip/hip_runtime.h>
#include <math.h>

#define ALPHA 0.5f
#define BETA  2.0e-4f   // 0.02 * 0.1 * 0.1
#define DELTA 0.1f
#define N_ITER 10

#define DD 192
#define HH 192
#define WW 192
#define HWW (192*192)
#define CHE 16         // err kernel: y-rows per block
#define CHU 12         // upd kernel: y-rows per block
#define XT  64         // upd kernel: x-tile width (one wave)
#define NSMAX 4        // err slices touching a z-pair window (stride>=2 -> <=3)

// robust-TV single-neighbor term: acc += dv*w / sqrt(1 + dv*dv*w)
#define RT(v1, Wc) do { float dv_ = v0 - (v1); float dw_ = dv_ * (Wc);            \
    acc = fmaf(dw_, rsqrtf(fmaf(dv_, dw_, 1.0f)), acc); } while (0)

// 26 neighbors for an output on center plane pb (pa=z-1, pc=z+1 delay idx)
#define REG26(pa, pb, pc)                                                          \
    RT(nbm[pa][0], W3); RT(m[pa][0], W2); RT(nbp[pa][0], W3);                      \
    RT(nbm[pa][1], W2); RT(m[pa][1], W1); RT(nbp[pa][1], W2);                      \
    RT(nbm[pa][2], W3); RT(m[pa][2], W2); RT(nbp[pa][2], W3);                      \
    RT(nbm[pb][0], W2); RT(m[pb][0], W1); RT(nbp[pb][0], W2);                      \
    RT(nbm[pb][1], W1);                   RT(nbp[pb][1], W1);                      \
    RT(nbm[pb][2], W2); RT(m[pb][2], W1); RT(nbp[pb][2], W2);                      \
    RT(nbm[pc][0], W3); RT(m[pc][0], W2); RT(nbp[pc][0], W3);                      \
    RT(nbm[pc][1], W2); RT(m[pc][1], W1); RT(nbp[pc][1], W2);                      \
    RT(nbm[pc][2], W3); RT(m[pc][2], W2); RT(nbp[pc][2], W3);

// ---------------------------------------------------------------------------
// K1: err_xy[s] = conv_x(conv_y( A(x)[s] - slices[s], wy_flip ), wx_flip)
// (unchanged from round 4 — ~10.6 us/iter)
// ---------------------------------------------------------------------------
__global__ __launch_bounds__(192) void srr_err_k(
    const float* __restrict__ x, const float* __restrict__ slices,
    const float* __restrict__ psf, const int* __restrict__ stride_p,
    float* __restrict__ err_xy, int n_slices)
{
    __shared__ float spsf[125];
    __shared__ float wsum[16];
    __shared__ float wzs[5], wys[5], wxs[5];
    __shared__ float raw[5][2][200];   // raw x rows [plane][slot][2+x], halos 0
    __shared__ float erw[2][200];      // err rows [slot][2+x], halos 0

    const int t = threadIdx.x;
    if (t < 125) spsf[t] = psf[t];
    if (t >= 128 && t < 176) {         // zero halo cols: 10 raw rows + 2 erw rows
        int q = t - 128, row = q >> 2, p = q & 3;
        int col = (p < 2) ? p : (192 + p);
        if (row < 10) raw[row >> 1][row & 1][col] = 0.f;
        else          erw[row - 10][col] = 0.f;
    }
    __syncthreads();
    if (t < 5)               { float s=0; for (int k=0;k<25;++k) s+=spsf[t*25+k]; wsum[t]=s; }
    else if (t>=8 && t<13)   { int b=t-8;  float s=0; for(int a=0;a<5;++a) for(int c=0;c<5;++c) s+=spsf[a*25+b*5+c]; wsum[t-3]=s; }
    else if (t>=16 && t<21)  { int c=t-16; float s=0; for(int a=0;a<5;++a) for(int b=0;b<5;++b) s+=spsf[a*25+b*5+c]; wsum[t-6]=s; }
    __syncthreads();
    if (t == 0) {
        float T = wsum[0]+wsum[1]+wsum[2]+wsum[3]+wsum[4];
        float iT = 1.0f / T;
        for (int a=0;a<5;++a) wzs[a] = wsum[a]   * iT;
        for (int b=0;b<5;++b) wys[b] = wsum[5+b] * iT;
        for (int c=0;c<5;++c) wxs[c] = wsum[10+c];
    }
    __syncthreads();

    const int s  = blockIdx.x;
    const int y0 = blockIdx.y * CHE;
    const int stride = *stride_p;
    const int z = s * stride;

    float wzr[5], wyr[5], wxr[5], wyf[5], wxf[5];
    #pragma unroll
    for (int i = 0; i < 5; ++i) {
        wzr[i]=wzs[i]; wyr[i]=wys[i]; wxr[i]=wxs[i];
        wyf[i]=wys[4-i]; wxf[i]=wxs[4-i];          // flipped for the adjoint
    }

    const float* xp[5]; bool okp[5];
    #pragma unroll
    for (int a = 0; a < 5; ++a) {
        int zz = z + a - 2;
        okp[a] = (zz >= 0) && (zz < DD);
        xp[a] = x + (size_t)(okp[a] ? zz : 0) * HWW + (ptrdiff_t)(y0 - 4) * WW + t;
    }
    const float* spm = slices + (size_t)s * HWW + (ptrdiff_t)(y0 - 2) * WW + t;
    float*       epo = err_xy + (size_t)s * HWW + (size_t)y0 * WW + t;

    float xv[5];
    {
        bool yg = (y0 - 4 >= 0);
        #pragma unroll
        for (int a = 0; a < 5; ++a) { xv[a] = (okp[a] && yg) ? *xp[a] : 0.f; xp[a] += WW; }
    }
    float P[5] = {0.f,0.f,0.f,0.f,0.f};
    float Q[5] = {0.f,0.f,0.f,0.f,0.f};
    float er_prev = 0.f, sv = 0.f, svn = 0.f;

    for (int k = 0; k < CHE + 9; ++k) {
        const int yy = y0 - 4 + k;
        const int sl = k & 1;
        #pragma unroll
        for (int a = 0; a < 5; ++a) raw[a][sl][2 + t] = xv[a];
        erw[sl][2 + t] = er_prev;                  // err row (yy-3)
        __syncthreads();
        {   // prefetch x rows (yy+1) + slices row (yy-1); overlaps compute
            int yn = yy + 1;
            bool yg = (yn >= 0) && (yn < HH);
            #pragma unroll
            for (int a = 0; a < 5; ++a) { xv[a] = (okp[a] && yg) ? *xp[a] : 0.f; xp[a] += WW; }
            int yv = yy - 1;
            if (yv >= y0 - 2 && yv < y0 + CHE + 2) {
                svn = (yv >= 0 && yv < HH) ? *spm : 0.f;
                spm += WW;
            } else svn = 0.f;
        }
        // forward: A(x) row yy
        float cxz = 0.f;
        #pragma unroll
        for (int a = 0; a < 5; ++a) {
            float c4 = 0.f;
            #pragma unroll
            for (int c = 0; c < 5; ++c) c4 = fmaf(wxr[c], raw[a][sl][t + c], c4);
            cxz = fmaf(wzr[a], c4, cxz);
        }
        P[0]=fmaf(wyr[4],cxz,P[0]); P[1]=fmaf(wyr[3],cxz,P[1]); P[2]=fmaf(wyr[2],cxz,P[2]);
        P[3]=fmaf(wyr[1],cxz,P[3]); P[4]=fmaf(wyr[0],cxz,P[4]);
        {   // finalize err row (yy-2), staged next step
            int yr = yy - 2;
            er_prev = (yr >= 0 && yr < HH) ? (P[0] - sv) : 0.f;
        }
        sv = svn;
        // adjoint xy: x-conv staged err row (yy-3), flipped weights
        float ex = 0.f;
        #pragma unroll
        for (int c = 0; c < 5; ++c) ex = fmaf(wxf[c], erw[sl][t + c], ex);
        Q[0]=fmaf(wyf[4],ex,Q[0]); Q[1]=fmaf(wyf[3],ex,Q[1]); Q[2]=fmaf(wyf[2],ex,Q[2]);
        Q[3]=fmaf(wyf[1],ex,Q[3]); Q[4]=fmaf(wyf[0],ex,Q[4]);
        {   // store err_xy row (yy-5)
            int yq = yy - 5;
            if (yq >= y0) { *epo = Q[0]; epo += WW; }
        }
        P[0]=P[1]; P[1]=P[2]; P[2]=P[3]; P[3]=P[4]; P[4]=0.f;
        Q[0]=Q[1]; Q[1]=Q[2]; Q[2]=Q[3]; Q[3]=Q[4]; Q[4]=0.f;
    }
}

// ---------------------------------------------------------------------------
// K2: x_out = x - ALPHA*( At_z(err_xy) + BETA*dR(x) ), optional final relu.
// Single-wave blocks (64 threads) on a 64-wide x-tile: no workgroup barriers
// (wave-internal LDS ordering), 4608 one-wave blocks for latency hiding.
// Lanes 0-3 stage the 2+2 halo columns; local col = gx - x0 + 2.
// ---------------------------------------------------------------------------
__global__ __launch_bounds__(64) void srr_upd_k(
    const float* __restrict__ x, const float* __restrict__ err_xy,
    const float* __restrict__ psf, const int* __restrict__ stride_p,
    float* __restrict__ xout, int n_slices, int apply_relu)
{
    __shared__ float spsf[125];
    __shared__ float wsum[8];
    __shared__ float xr[4][4][72];             // [plane][row-slot][local x: 0..67]
    __shared__ int   s_cnt, s_sidx[NSMAX];
    __shared__ float s_w0[NSMAX], s_w1[NSMAX];

    const int t = threadIdx.x;
    spsf[t] = psf[t];
    if (t < 61) spsf[64 + t] = psf[64 + t];
    __syncthreads();
    if (t < 5) { float s=0; for (int k=0;k<25;++k) s+=spsf[t*25+k]; wsum[t]=s; }
    __syncthreads();
    const int z0 = 2 * blockIdx.x;
    if (t == 0) {
        float T = wsum[0]+wsum[1]+wsum[2]+wsum[3]+wsum[4];
        float iT = 1.0f / T;
        float wzf[5];
        for (int a=0;a<5;++a) wzf[a] = wsum[4-a] * iT;   // flipped z weights
        int stride = *stride_p;
        int cnt = 0;
        for (int d = -2; d <= 3; ++d) {        // err planes z0-2 .. z0+3
            int zz = z0 + d;
            if (zz >= 0 && zz < DD && (zz % stride) == 0) {
                int ss = zz / stride;
                if (ss < n_slices && cnt < NSMAX) {
                    s_sidx[cnt] = ss;
                    s_w0[cnt] = (d <= 2)  ? wzf[d + 2] : 0.f;   // weight for z0
                    s_w1[cnt] = (d >= -1) ? wzf[d + 1] : 0.f;   // weight for z0+1
                    ++cnt;
                }
            }
        }
        s_cnt = cnt;
    }
    __syncthreads();

    const int x0  = blockIdx.y * XT;
    const int y0  = blockIdx.z * CHU;
    const int cnt = s_cnt;
    const int gx  = x0 + t;

    float w0r[NSMAX], w1r[NSMAX];
    const float* ep[NSMAX];
    #pragma unroll
    for (int j = 0; j < NSMAX; ++j) {
        bool v = (j < cnt);
        w0r[j] = v ? s_w0[j] : 0.f;
        w1r[j] = v ? s_w1[j] : 0.f;
        ep[j] = err_xy + (size_t)(v ? s_sidx[j] : 0) * HWW + (size_t)y0 * WW + gx;
    }
    const float* xp[4]; bool okp[4];
    #pragma unroll
    for (int zo = 0; zo < 4; ++zo) {
        int zz = z0 - 1 + zo;
        okp[zo] = (zz >= 0) && (zz < DD);
        xp[zo] = x + (size_t)(okp[zo] ? zz : 0) * HWW + (ptrdiff_t)(y0 - 2) * WW + gx;
    }
    // halo columns: lanes 0,1 -> local 0,1 (gx = x0-2,x0-1);
    //               lanes 2,3 -> local 66,67 (gx = x0+64,x0+65); local = gx-x0+2
    const int  hloc = (t < 2) ? t : (64 + t);   // 0,1,66,67 for t<4
    const int  hgx  = x0 - 2 + hloc;            // x0-2,x0-1,x0+64,x0+65
    const bool hol  = (t < 4) && (hgx >= 0) && (hgx < WW);
    const int  hgxc = (hgx < 0) ? 0 : ((hgx > WW - 1) ? (WW - 1) : hgx);
    const float* hp[4];
    #pragma unroll
    for (int zo = 0; zo < 4; ++zo) {
        int zz = z0 - 1 + zo;
        hp[zo] = x + (size_t)(okp[zo] ? zz : 0) * HWW + (ptrdiff_t)(y0 - 2) * WW + hgxc;
    }
    float* op0 = xout + (size_t)z0 * HWW       + (size_t)y0 * WW + gx;
    float* op1 = xout + (size_t)(z0 + 1) * HWW + (size_t)y0 * WW + gx;
    const bool okz0 = (z0 >= 1);
    const bool okz1 = (z0 + 1 <= DD - 2);
    const bool tok  = (gx >= 1) && (gx <= WW - 2);

    float xv[4], hxv[4];
    {
        bool yg = (y0 - 2 >= 0);
        #pragma unroll
        for (int zo = 0; zo < 4; ++zo) {
            xv[zo]  = (okp[zo] && yg)        ? *xp[zo] : 0.f; xp[zo] += WW;
            hxv[zo] = (hol && okp[zo] && yg) ? *hp[zo] : 0.f; hp[zo] += WW;
        }
    }
    float m[4][3];
    #pragma unroll
    for (int zo = 0; zo < 4; ++zo) { m[zo][0]=0.f; m[zo][1]=0.f; m[zo][2]=0.f; }
    float ev[NSMAX], evn[NSMAX];
    #pragma unroll
    for (int j = 0; j < NSMAX; ++j) { ev[j]=0.f; evn[j]=0.f; }
    float rr0 = 0.f, rr1 = 0.f;

    const float W1 = 1.0f / (1.0f * DELTA * DELTA);
    const float W2 = 1.0f / (2.0f * DELTA * DELTA);
    const float W3 = 1.0f / (3.0f * DELTA * DELTA);

    for (int k = 0; k < CHU + 4; ++k) {
        const int yy  = y0 - 2 + k;
        const int sl4 = k & 3;
        #pragma unroll
        for (int zo = 0; zo < 4; ++zo) xr[zo][sl4][2 + t] = xv[zo];
        if (t < 4) {
            #pragma unroll
            for (int zo = 0; zo < 4; ++zo) xr[zo][sl4][hloc] = hxv[zo];
        }
        // single wave: no barrier needed; DS ordering is program-order
        #pragma unroll
        for (int zo = 0; zo < 4; ++zo) { m[zo][0]=m[zo][1]; m[zo][1]=m[zo][2]; m[zo][2]=xv[zo]; }
        {   // prefetch x rows (yy+1) and err_xy rows (yy-1); overlaps compute
            int yn = yy + 1;
            bool yg = (yn >= 0) && (yn < HH);
            #pragma unroll
            for (int zo = 0; zo < 4; ++zo) {
                xv[zo]  = (okp[zo] && yg)        ? *xp[zo] : 0.f; xp[zo] += WW;
                hxv[zo] = (hol && okp[zo] && yg) ? *hp[zo] : 0.f; hp[zo] += WW;
            }
            int r = yy - 1;
            if (r >= y0 && r < y0 + CHU) {
                #pragma unroll
                for (int j = 0; j < NSMAX; ++j) {
                    if (j < cnt) { evn[j] = *ep[j]; ep[j] += WW; }
                }
            }
        }
        // store y_s = yy-2 (uses ev + rr from previous step)
        if (yy - 2 >= y0) {
            float g0 = 0.f, g1 = 0.f;
            #pragma unroll
            for (int j = 0; j < NSMAX; ++j) {
                g0 = fmaf(w0r[j], ev[j], g0);
                g1 = fmaf(w1r[j], ev[j], g1);
            }
            float o0 = m[1][0] - ALPHA * (g0 + BETA * rr0);
            float o1 = m[2][0] - ALPHA * (g1 + BETA * rr1);
            if (apply_relu) { o0 = fmaxf(o0, 0.f); o1 = fmaxf(o1, 0.f); }
            *op0 = o0; op0 += WW;
            *op1 = o1; op1 += WW;
        }
        #pragma unroll
        for (int j = 0; j < NSMAX; ++j) ev[j] = evn[j];
        // regularizer for y_r = yy-1 (consumed next step)
        const int yr = yy - 1;
        if (yr >= y0 && yr < y0 + CHU) {
            const bool oky = (yr >= 1) && (yr <= HH - 2);
            const int rs0 = (k + 2) & 3, rs1 = (k + 3) & 3, rs2 = k & 3;
            float nbm[4][3], nbp[4][3];
            #pragma unroll
            for (int zo = 0; zo < 4; ++zo) {
                nbm[zo][0] = xr[zo][rs0][1 + t]; nbp[zo][0] = xr[zo][rs0][3 + t];
                nbm[zo][1] = xr[zo][rs1][1 + t]; nbp[zo][1] = xr[zo][rs1][3 + t];
                nbm[zo][2] = xr[zo][rs2][1 + t]; nbp[zo][2] = xr[zo][rs2][3 + t];
            }
            {
                float v0 = m[1][1]; float acc = 0.f;
                REG26(0, 1, 2);
                rr0 = (okz0 && oky && tok) ? acc : 0.f;
            }
            {
                float v0 = m[2][1]; float acc = 0.f;
                REG26(1, 2, 3);
                rr1 = (okz1 && oky && tok) ? acc : 0.f;
            }
        } else { rr0 = 0.f; rr1 = 0.f; }
    }
}

extern "C" void kernel_launch(void* const* d_in, const int* in_sizes, int n_in,
                              void* d_out, int out_size, void* d_ws, size_t ws_size,
                              hipStream_t stream) {
    // inputs: 0=theta (unused), 1=slices, 2=volume, 3=psf, 4=stride
    const float* slices = (const float*)d_in[1];
    const float* volume = (const float*)d_in[2];
    const float* psf    = (const float*)d_in[3];
    const int*   strd   = (const int*)d_in[4];

    const int n_slices = in_sizes[1] / (HH * WW);   // 96

    float* x_ws   = (float*)d_ws;                   // 192^3 floats
    float* err_xy = x_ws + (size_t)DD * HH * WW;    // n_slices*H*W floats
    float* x_out  = (float*)d_out;                  // pong buffer / final output

    dim3 blkE(192, 1, 1);
    dim3 gA(n_slices, HH / CHE);            // 96 x 12
    dim3 blkU(XT, 1, 1);
    dim3 gB(DD / 2, WW / XT, HH / CHU);     // 96 x 3 x 16 = 4608 one-wave blocks

    const float* src = volume;
    for (int it = 0; it < N_ITER; ++it) {
        float* dst = (it & 1) ? x_out : x_ws;
        srr_err_k<<<gA, blkE, 0, stream>>>(src, slices, psf, strd, err_xy, n_slices);
        srr_upd_k<<<gB, blkU, 0, stream>>>(src, err_xy, psf, strd, dst, n_slices,
                                           (it == N_ITER - 1) ? 1 : 0);
        src = dst;
    }
}